// Round 9
// baseline (330.578 us; speedup 1.0000x reference)
//
#include <hip/hip_runtime.h>
#include <hip/hip_bf16.h>

// KAN layer as one bf16 GEMM: out[8192,512] = A[8192,7168] @ W[512,7168]^T + b
// A layout is BASIS-MAJOR: col k = plane*512 + i, plane 0 = silu(x_i),
// planes 1..13 = b-spline bases g=0..12 of x_i. W permuted to match.
// R3: m97-style GEMM (global_load_lds w16, 128x128 tile) + split-K partials.
// R4: prep rewritten — register-only, __expf, coalesced ushort2 plane stores.
// R5: LDS XOR bank swizzle -> conflicts 2.2e7 -> 0 (for 16x16 reads).
// R6: 32x32x16 MFMA (VALUBusy 35->11%) + bf16 partials.
// R7: row-aware swizzle key (R&7)^((R>>3)&7) -> conflicts 0, gemm 75.5us.
// R8: ksplit 4->2 (fewer blocks won: gemm 72.6us) + wconv merged into prep.
// R9: reduce fused into gemm epilogue via per-tile flag race (threadfence +
//     device-scope atomicAdd, G16-safe): both ks blocks write bf16 partial,
//     second finisher adds partner's slab to its fp32 acc + bias -> out.
//     Kills the reduce dispatch and ~96KB/tile of HBM traffic. K-loop untouched.

#define BATCH   8192
#define IN_F    512
#define N_OUT   512
#define NG      13            // GRID_SIZE + K
#define NPL     14            // planes: silu + 13 bases
#define K_TOT   7168          // 14 * 512
#define BM      128
#define BN      128
#define BK      64
#define KSMAX   2

typedef short short8 __attribute__((ext_vector_type(8)));
typedef float floatx16 __attribute__((ext_vector_type(16)));

__device__ __forceinline__ unsigned short f2bf(float f) {
    union { float f; unsigned u; } v; v.f = f;
    unsigned r = v.u + 0x7FFFu + ((v.u >> 16) & 1u);   // RNE
    return (unsigned short)(r >> 16);
}
__device__ __forceinline__ float bf2f(unsigned short h) {
    union { unsigned u; float f; } v; v.u = (unsigned)h << 16;
    return v.f;
}

__device__ __forceinline__ void gl2lds16(const unsigned short* g, unsigned short* l) {
    __builtin_amdgcn_global_load_lds(
        (const __attribute__((address_space(1))) unsigned int*)g,
        (__attribute__((address_space(3))) unsigned int*)l, 16, 0, 0);
}

// ---------------- aux: prep (blocks [0,nprep)) + wconv (blocks [nprep,nprep+nw)) ----
__global__ __launch_bounds__(256)
void kan_aux(const float* __restrict__ X,
             unsigned short* __restrict__ A,
             const float* __restrict__ base_w,
             const float* __restrict__ spline_w,
             unsigned short* __restrict__ Wb,
             int row0, int nprep) {
    if ((int)blockIdx.x >= nprep) {
        // ---- wconv part: Wb[o][pl*512+i] ----
        int o = blockIdx.x - nprep;            // 0..511
        for (int c = threadIdx.x; c < K_TOT; c += 256) {
            int pl = c >> 9;
            int i  = c & 511;
            float v = (pl == 0) ? base_w[o * IN_F + i]
                                : spline_w[(long)o * (IN_F * NG) + i * NG + (pl - 1)];
            Wb[(long)o * K_TOT + c] = f2bf(v);
        }
        return;
    }
    // ---- prep part: one block per batch row ----
    const int b  = blockIdx.x;
    const int ip = threadIdx.x;                // feature pair 0..255
    float2 x2 = ((const float2*)(X + (long)(row0 + b) * IN_F))[ip];

    float outv[2][NPL];
#pragma unroll
    for (int e = 0; e < 2; e++) {
        float x = (e == 0) ? x2.x : x2.y;
        outv[e][0] = x * __builtin_amdgcn_rcpf(1.0f + __expf(-x));  // silu

        // cubic Cox-de Boor on uniform knots t_j = -3.2 + 0.4j
        float bb[16];
#pragma unroll
        for (int j = 0; j < 16; j++) {
            float t0 = -3.2f + 0.4f * j;
            bb[j] = (x >= t0 && x < t0 + 0.4f) ? 1.0f : 0.0f;
        }
        const float inv1 = 1.0f / (0.4f + 1e-8f);
        const float inv2 = 1.0f / (0.8f + 1e-8f);
        const float inv3 = 1.0f / (1.2f + 1e-8f);
#pragma unroll
        for (int j = 0; j < 15; j++) {
            float tj = -3.2f + 0.4f * j;
            bb[j] = (x - tj) * inv1 * bb[j] + ((tj + 0.8f) - x) * inv1 * bb[j + 1];
        }
#pragma unroll
        for (int j = 0; j < 14; j++) {
            float tj = -3.2f + 0.4f * j;
            bb[j] = (x - tj) * inv2 * bb[j] + ((tj + 1.2f) - x) * inv2 * bb[j + 1];
        }
#pragma unroll
        for (int j = 0; j < 13; j++) {
            float tj = -3.2f + 0.4f * j;
            bb[j] = (x - tj) * inv3 * bb[j] + ((tj + 1.6f) - x) * inv3 * bb[j + 1];
        }
#pragma unroll
        for (int g = 0; g < NG; g++) outv[e][1 + g] = bb[g];
    }

    unsigned short* arow = A + (long)b * K_TOT + ip * 2;
#pragma unroll
    for (int pl = 0; pl < NPL; pl++) {
        unsigned int pk = (unsigned int)f2bf(outv[0][pl]) |
                          ((unsigned int)f2bf(outv[1][pl]) << 16);
        *(unsigned int*)(arow + pl * IN_F) = pk;
    }
}

// ---------------- GEMM: m97 structure + row-aware swizzle, 32x32x16 MFMA,
//                  fused split-K combine via flag race ----------------
__global__ __launch_bounds__(256)
void kan_gemm(const unsigned short* __restrict__ A,   // [chunk][7168] bf16 bits
              const unsigned short* __restrict__ Wb,  // [512][7168]  bf16 bits
              const float* __restrict__ bias,         // [512]
              float* __restrict__ out,                // [8192][512] fp32
              unsigned short* __restrict__ part,      // [tile][ks][128*128] bf16
              unsigned int* __restrict__ flags,       // [ntiles], zeroed
              int row0, int kiters, int nks) {
    __shared__ unsigned short As[BM * BK];   // 16 KB; swizzled layout:
    __shared__ unsigned short Bs[BN * BK];   // chunk J of row R at pos J^(R&7)^((R>>3)&7)

    const int lane = threadIdx.x & 63;
    const int wave = threadIdx.x >> 6;
    const int wm   = wave >> 1;      // 0..1
    const int wn   = wave & 1;       // 0..1
    const int l32  = lane & 31;      // mfma 32x32 row/col index
    const int hi   = lane >> 5;      // mfma k-half
    const int x7   = lane & 7;       // low swizzle key bits
    const int b32  = l32 >> 3;       // row bits 3-4 within a 32-row fragment

    const int m0 = blockIdx.x * BM;          // row within chunk
    const int n0 = blockIdx.y * BN;
    const int ks = blockIdx.z;
    const long kbase = (long)ks * kiters * BK;

    // staging: instr q of wave w covers rows w*32+q*8+sr; lane l fetches
    // global chunk (l&7) ^ key(R), key(R) = (R&7)^((R>>3)&7) = sr^(4*(w&1)+q)
    const int sr = lane >> 3;                // 0..7

    const unsigned short* gA[4];
    const unsigned short* gB[4];
#pragma unroll
    for (int q = 0; q < 4; q++) {
        int scs = ((lane & 7) ^ sr ^ ((4 * (wave & 1) + q) & 7)) * 8;
        gA[q] = A  + (long)(m0 + wave * 32 + q * 8 + sr) * K_TOT + kbase + scs;
        gB[q] = Wb + (long)(n0 + wave * 32 + q * 8 + sr) * K_TOT + kbase + scs;
    }
    unsigned short* lA = As + (wave * 32) * BK;   // wave-uniform base
    unsigned short* lB = Bs + (wave * 32) * BK;

    floatx16 acc[2][2];
#pragma unroll
    for (int i = 0; i < 2; i++)
#pragma unroll
        for (int j = 0; j < 2; j++)
#pragma unroll
            for (int r = 0; r < 16; r++) acc[i][j][r] = 0.0f;

    for (int kk = 0; kk < kiters; kk++) {
        __syncthreads();                     // prior compute done before overwrite
#pragma unroll
        for (int q = 0; q < 4; q++) {
            gl2lds16(gA[q], lA + q * 8 * BK);
            gl2lds16(gB[q], lB + q * 8 * BK);
            gA[q] += BK; gB[q] += BK;
        }
        __syncthreads();                     // drains vmcnt (compiler-inserted)

#pragma unroll
        for (int s = 0; s < 4; s++) {        // four k=16 MFMA steps per BK=64
            short8 af[2], bf[2];
#pragma unroll
            for (int t = 0; t < 2; t++) {    // physical chunk = J ^ key(row)
                const int cofs = (((2 * s + hi) ^ x7 ^ (4 * t) ^ b32) & 7) * 8;
                af[t] = *(const short8*)(As + (wm * 64 + t * 32 + l32) * BK + cofs);
                bf[t] = *(const short8*)(Bs + (wn * 64 + t * 32 + l32) * BK + cofs);
            }
#pragma unroll
            for (int i = 0; i < 2; i++)
#pragma unroll
                for (int j = 0; j < 2; j++)
                    acc[i][j] = __builtin_amdgcn_mfma_f32_32x32x16_bf16(
                        af[i], bf[j], acc[i][j], 0, 0, 0);
        }
    }

    // ---- fused split-K combine (nks==2): flag race picks the combiner ----
    if (nks == 2) {
        const int tile = blockIdx.x * (N_OUT / BN) + blockIdx.y;
        // write my partial: thread-contiguous 128B (8 x uint4), bf16 pairs
        unsigned int* myp = (unsigned int*)part +
                            ((long)tile * 2 + ks) * (BM * BN / 2) + threadIdx.x * 32;
#pragma unroll
        for (int i = 0; i < 2; i++)
#pragma unroll
            for (int j = 0; j < 2; j++)
#pragma unroll
                for (int p = 0; p < 8; p++)
                    myp[(i * 2 + j) * 8 + p] =
                        (unsigned)f2bf(acc[i][j][2 * p]) |
                        ((unsigned)f2bf(acc[i][j][2 * p + 1]) << 16);
        __threadfence();                               // release partial
        unsigned old = atomicAdd(&flags[tile], 1u);    // device-scope
        if (old == 0) return;                          // first finisher: done
        __threadfence();                               // acquire partner's data
        const unsigned int* pp = (const unsigned int*)part +
                            ((long)tile * 2 + (1 - ks)) * (BM * BN / 2) + threadIdx.x * 32;
#pragma unroll
        for (int i = 0; i < 2; i++)
#pragma unroll
            for (int j = 0; j < 2; j++)
#pragma unroll
                for (int p = 0; p < 8; p++) {
                    unsigned u = pp[(i * 2 + j) * 8 + p];
                    acc[i][j][2 * p]     += bf2f((unsigned short)(u & 0xffff));
                    acc[i][j][2 * p + 1] += bf2f((unsigned short)(u >> 16));
                }
    }

    // ---- direct out store with bias (combiner, or nks==1) ----
    // 32x32 C/D layout: col=lane&31, row=(reg&3)+8*(reg>>2)+4*hi
    float* dst = out + (long)row0 * N_OUT;
#pragma unroll
    for (int i = 0; i < 2; i++) {
        int r0 = m0 + wm * 64 + i * 32 + 4 * hi;
#pragma unroll
        for (int j = 0; j < 2; j++) {
            int col = n0 + wn * 64 + j * 32 + l32;
            float bv = bias[col];
#pragma unroll
            for (int reg = 0; reg < 16; reg++) {
                int row = r0 + (reg & 3) + 8 * (reg >> 2);
                dst[(long)row * N_OUT + col] = acc[i][j][reg] + bv;
            }
        }
    }
}

extern "C" void kernel_launch(void* const* d_in, const int* in_sizes, int n_in,
                              void* d_out, int out_size, void* d_ws, size_t ws_size,
                              hipStream_t stream) {
    const float* x        = (const float*)d_in[0];
    const float* base_w   = (const float*)d_in[1];
    const float* base_b   = (const float*)d_in[2];
    const float* spline_w = (const float*)d_in[3];
    float* out = (float*)d_out;

    unsigned short* Wb = (unsigned short*)d_ws;            // 512*7168 bf16
    const size_t wbytes = (size_t)N_OUT * K_TOT * 2;       // 7.34 MB

    // pick largest chunk (then ksplit) that fits ws:
    //   ws = Wb + A[chunk][7168] bf16 + part[ntiles][2][128*128] bf16 + flags
    int chunk = BATCH, ksplit = KSMAX;
    while (chunk > 128 &&
           wbytes + (size_t)chunk * K_TOT * 2 +
           (size_t)chunk * N_OUT * 2 * KSMAX +
           (size_t)(chunk / BM) * (N_OUT / BN) * 4 > ws_size) chunk >>= 1;
    if (wbytes + (size_t)chunk * K_TOT * 2 +
        (size_t)chunk * N_OUT * 2 * KSMAX +
        (size_t)(chunk / BM) * (N_OUT / BN) * 4 > ws_size) ksplit = 1;

    unsigned short* Abuf = Wb + (size_t)N_OUT * K_TOT;
    unsigned short* part = Abuf + (size_t)chunk * K_TOT;
    unsigned int* flags = (unsigned int*)(part + (size_t)chunk * N_OUT * KSMAX);
    const int kiters = (K_TOT / BK) / ksplit;              // 112/ks, exact
    const int ntiles = (chunk / BM) * (N_OUT / BN);

    bool first = true;
    for (int row0 = 0; row0 < BATCH; row0 += chunk) {
        int nw = first ? N_OUT : 0;                        // wconv rides launch 1
        first = false;
        kan_aux<<<dim3(chunk + nw), 256, 0, stream>>>(
            x, Abuf, base_w, spline_w, Wb, row0, chunk);
        if (ksplit > 1)
            hipMemsetAsync(flags, 0, ntiles * sizeof(unsigned), stream);
        kan_gemm<<<dim3(chunk / BM, N_OUT / BN, ksplit), 256, 0, stream>>>(
            Abuf, Wb, base_b, out, part, flags, row0, kiters, ksplit);
    }
}

// Round 10
// 182.817 us; speedup vs baseline: 1.8082x; 1.8082x over previous
//
#include <hip/hip_runtime.h>
#include <hip/hip_bf16.h>

// KAN layer as one bf16 GEMM: out[8192,512] = A[8192,7168] @ W[512,7168]^T + b
// A layout is BASIS-MAJOR: col k = plane*512 + i, plane 0 = silu(x_i),
// planes 1..13 = b-spline bases g=0..12 of x_i. W permuted to match.
// R3: m97-style GEMM (global_load_lds w16, 128x128 tile) + split-K partials.
// R4: prep rewritten — register-only, __expf, coalesced ushort2 plane stores.
// R5: LDS XOR bank swizzle -> conflicts 2.2e7 -> 0 (for 16x16 reads).
// R6: 32x32x16 MFMA (VALUBusy 35->11%) + bf16 partials.
// R7: row-aware swizzle key (R&7)^((R>>3)&7) -> conflicts 0, gemm 75.5us.
// R8: ksplit 4->2 + wconv merged into prep launch. gemm 72.6us, total 178.
// R9 FAILED (244us gemm): fused flag-race combine — per-thread-contiguous
//     partial slab made every store/load 64-transaction (lanes 128B apart),
//     L2-port storm + device-scope fences stalled co-resident K-loops. Reverted.
// R10: R8 + double-buffered LDS (one barrier/iter, staging overlaps compute;
//      m99/m100 pattern). LDS 32->64KB still 2 blocks/CU.

#define BATCH   8192
#define IN_F    512
#define N_OUT   512
#define NG      13            // GRID_SIZE + K
#define NPL     14            // planes: silu + 13 bases
#define K_TOT   7168          // 14 * 512
#define BM      128
#define BN      128
#define BK      64
#define KSMAX   2

typedef short short8 __attribute__((ext_vector_type(8)));
typedef float floatx16 __attribute__((ext_vector_type(16)));

__device__ __forceinline__ unsigned short f2bf(float f) {
    union { float f; unsigned u; } v; v.f = f;
    unsigned r = v.u + 0x7FFFu + ((v.u >> 16) & 1u);   // RNE
    return (unsigned short)(r >> 16);
}
__device__ __forceinline__ float bf2f(unsigned short h) {
    union { unsigned u; float f; } v; v.u = (unsigned)h << 16;
    return v.f;
}

__device__ __forceinline__ void gl2lds16(const unsigned short* g, unsigned short* l) {
    __builtin_amdgcn_global_load_lds(
        (const __attribute__((address_space(1))) unsigned int*)g,
        (__attribute__((address_space(3))) unsigned int*)l, 16, 0, 0);
}

// ---------------- aux: prep (blocks [0,nprep)) + wconv (blocks [nprep,nprep+nw)) ----
__global__ __launch_bounds__(256)
void kan_aux(const float* __restrict__ X,
             unsigned short* __restrict__ A,
             const float* __restrict__ base_w,
             const float* __restrict__ spline_w,
             unsigned short* __restrict__ Wb,
             int row0, int nprep) {
    if ((int)blockIdx.x >= nprep) {
        // ---- wconv part: Wb[o][pl*512+i] ----
        int o = blockIdx.x - nprep;            // 0..511
        for (int c = threadIdx.x; c < K_TOT; c += 256) {
            int pl = c >> 9;
            int i  = c & 511;
            float v = (pl == 0) ? base_w[o * IN_F + i]
                                : spline_w[(long)o * (IN_F * NG) + i * NG + (pl - 1)];
            Wb[(long)o * K_TOT + c] = f2bf(v);
        }
        return;
    }
    // ---- prep part: one block per batch row ----
    const int b  = blockIdx.x;
    const int ip = threadIdx.x;                // feature pair 0..255
    float2 x2 = ((const float2*)(X + (long)(row0 + b) * IN_F))[ip];

    float outv[2][NPL];
#pragma unroll
    for (int e = 0; e < 2; e++) {
        float x = (e == 0) ? x2.x : x2.y;
        outv[e][0] = x * __builtin_amdgcn_rcpf(1.0f + __expf(-x));  // silu

        // cubic Cox-de Boor on uniform knots t_j = -3.2 + 0.4j
        float bb[16];
#pragma unroll
        for (int j = 0; j < 16; j++) {
            float t0 = -3.2f + 0.4f * j;
            bb[j] = (x >= t0 && x < t0 + 0.4f) ? 1.0f : 0.0f;
        }
        const float inv1 = 1.0f / (0.4f + 1e-8f);
        const float inv2 = 1.0f / (0.8f + 1e-8f);
        const float inv3 = 1.0f / (1.2f + 1e-8f);
#pragma unroll
        for (int j = 0; j < 15; j++) {
            float tj = -3.2f + 0.4f * j;
            bb[j] = (x - tj) * inv1 * bb[j] + ((tj + 0.8f) - x) * inv1 * bb[j + 1];
        }
#pragma unroll
        for (int j = 0; j < 14; j++) {
            float tj = -3.2f + 0.4f * j;
            bb[j] = (x - tj) * inv2 * bb[j] + ((tj + 1.2f) - x) * inv2 * bb[j + 1];
        }
#pragma unroll
        for (int j = 0; j < 13; j++) {
            float tj = -3.2f + 0.4f * j;
            bb[j] = (x - tj) * inv3 * bb[j] + ((tj + 1.6f) - x) * inv3 * bb[j + 1];
        }
#pragma unroll
        for (int g = 0; g < NG; g++) outv[e][1 + g] = bb[g];
    }

    unsigned short* arow = A + (long)b * K_TOT + ip * 2;
#pragma unroll
    for (int pl = 0; pl < NPL; pl++) {
        unsigned int pk = (unsigned int)f2bf(outv[0][pl]) |
                          ((unsigned int)f2bf(outv[1][pl]) << 16);
        *(unsigned int*)(arow + pl * IN_F) = pk;
    }
}

// ---------------- GEMM: dbuf LDS + row-aware swizzle, 32x32x16 MFMA ----------------
__global__ __launch_bounds__(256)
void kan_gemm(const unsigned short* __restrict__ A,   // [chunk][7168] bf16 bits
              const unsigned short* __restrict__ Wb,  // [512][7168]  bf16 bits
              const float* __restrict__ bias,         // [512]
              float* __restrict__ out,                // [8192][512] fp32
              unsigned short* __restrict__ part,      // [(ks-1)][chunk][512] bf16
              int row0, int kiters, int chunk) {
    __shared__ unsigned short As[2 * BM * BK];   // 2 x 16 KB, swizzled:
    __shared__ unsigned short Bs[2 * BN * BK];   // chunk J of row R at J^(R&7)^((R>>3)&7)

    const int lane = threadIdx.x & 63;
    const int wave = threadIdx.x >> 6;
    const int wm   = wave >> 1;      // 0..1
    const int wn   = wave & 1;       // 0..1
    const int l32  = lane & 31;      // mfma 32x32 row/col index
    const int hi   = lane >> 5;      // mfma k-half
    const int x7   = lane & 7;       // low swizzle key bits
    const int b32  = l32 >> 3;       // row bits 3-4 within a 32-row fragment

    const int m0 = blockIdx.x * BM;          // row within chunk
    const int n0 = blockIdx.y * BN;
    const int ks = blockIdx.z;
    const long kbase = (long)ks * kiters * BK;

    // staging: instr q of wave w covers rows w*32+q*8+sr; lane l fetches
    // global chunk (l&7) ^ key(R), key(R) = (R&7)^((R>>3)&7) = sr^(4*(w&1)+q)
    const int sr = lane >> 3;                // 0..7

    const unsigned short* gA[4];
    const unsigned short* gB[4];
#pragma unroll
    for (int q = 0; q < 4; q++) {
        int scs = ((lane & 7) ^ sr ^ ((4 * (wave & 1) + q) & 7)) * 8;
        gA[q] = A  + (long)(m0 + wave * 32 + q * 8 + sr) * K_TOT + kbase + scs;
        gB[q] = Wb + (long)(n0 + wave * 32 + q * 8 + sr) * K_TOT + kbase + scs;
    }

    floatx16 acc[2][2];
#pragma unroll
    for (int i = 0; i < 2; i++)
#pragma unroll
        for (int j = 0; j < 2; j++)
#pragma unroll
            for (int r = 0; r < 16; r++) acc[i][j][r] = 0.0f;

    auto stage = [&](int buf) {
        unsigned short* a = As + buf * (BM * BK) + (wave * 32) * BK;
        unsigned short* b = Bs + buf * (BM * BK) + (wave * 32) * BK;
#pragma unroll
        for (int q = 0; q < 4; q++) {
            gl2lds16(gA[q], a + q * 8 * BK);
            gl2lds16(gB[q], b + q * 8 * BK);
            gA[q] += BK; gB[q] += BK;
        }
    };
    auto compute = [&](int buf) {
        const unsigned short* a0 = As + buf * (BM * BK);
        const unsigned short* b0 = Bs + buf * (BM * BK);
#pragma unroll
        for (int s = 0; s < 4; s++) {        // four k=16 MFMA steps per BK=64
            short8 af[2], bf[2];
#pragma unroll
            for (int t = 0; t < 2; t++) {    // physical chunk = J ^ key(row)
                const int cofs = (((2 * s + hi) ^ x7 ^ (4 * t) ^ b32) & 7) * 8;
                af[t] = *(const short8*)(a0 + (wm * 64 + t * 32 + l32) * BK + cofs);
                bf[t] = *(const short8*)(b0 + (wn * 64 + t * 32 + l32) * BK + cofs);
            }
#pragma unroll
            for (int i = 0; i < 2; i++)
#pragma unroll
                for (int j = 0; j < 2; j++)
                    acc[i][j] = __builtin_amdgcn_mfma_f32_32x32x16_bf16(
                        af[i], bf[j], acc[i][j], 0, 0, 0);
        }
    };

    // double-buffered pipeline, one barrier per k-iter (kiters is even)
    stage(0);
    for (int kk = 0; kk < kiters; kk += 2) {
        __syncthreads();                     // buf0 loads done; buf1 compute done
        stage(1);                            // prefetch next tile into buf1
        compute(0);
        __syncthreads();                     // buf1 loads done; buf0 compute done
        if (kk + 2 < kiters) stage(0);       // prefetch into buf0
        compute(1);
    }

    // epilogue: 32x32 C/D layout col=lane&31, row=(reg&3)+8*(reg>>2)+4*hi
    if (ks == 0) {
        float* dst = out + (long)row0 * N_OUT;
#pragma unroll
        for (int i = 0; i < 2; i++) {
            int r0 = m0 + wm * 64 + i * 32 + 4 * hi;
#pragma unroll
            for (int j = 0; j < 2; j++) {
                int col = n0 + wn * 64 + j * 32 + l32;
                float bv = bias[col];
#pragma unroll
                for (int reg = 0; reg < 16; reg++) {
                    int row = r0 + (reg & 3) + 8 * (reg >> 2);
                    dst[(long)row * N_OUT + col] = acc[i][j][reg] + bv;
                }
            }
        }
    } else {
        unsigned short* dst = part + (long)(ks - 1) * chunk * N_OUT;
#pragma unroll
        for (int i = 0; i < 2; i++) {
            int r0 = m0 + wm * 64 + i * 32 + 4 * hi;
#pragma unroll
            for (int j = 0; j < 2; j++) {
                int col = n0 + wn * 64 + j * 32 + l32;
#pragma unroll
                for (int reg = 0; reg < 16; reg++) {
                    int row = r0 + (reg & 3) + 8 * (reg >> 2);
                    dst[(long)row * N_OUT + col] = f2bf(acc[i][j][reg]);
                }
            }
        }
    }
}

// ---------------- partial reduction: out += sum(bf16 partials) ----------------
__global__ void kan_reduce(float* __restrict__ out,               // chunk*512 fp32
                           const unsigned short* __restrict__ part,
                           int ns, long n4) {                     // n4 = chunk*512/4
    long t = (long)blockIdx.x * 256 + threadIdx.x;
    if (t >= n4) return;
    float4 v = ((const float4*)out)[t];
    for (int s = 0; s < ns; s++) {
        ushort4 p = ((const ushort4*)part)[s * n4 + t];
        v.x += bf2f(p.x); v.y += bf2f(p.y); v.z += bf2f(p.z); v.w += bf2f(p.w);
    }
    ((float4*)out)[t] = v;
}

extern "C" void kernel_launch(void* const* d_in, const int* in_sizes, int n_in,
                              void* d_out, int out_size, void* d_ws, size_t ws_size,
                              hipStream_t stream) {
    const float* x        = (const float*)d_in[0];
    const float* base_w   = (const float*)d_in[1];
    const float* base_b   = (const float*)d_in[2];
    const float* spline_w = (const float*)d_in[3];
    float* out = (float*)d_out;

    unsigned short* Wb = (unsigned short*)d_ws;            // 512*7168 bf16
    const size_t wbytes = (size_t)N_OUT * K_TOT * 2;       // 7.34 MB

    // pick largest chunk (then largest ksplit) that fits ws:
    //   ws = Wb + A[chunk][7168] bf16 + partials (ksplit-1)*chunk*512 bf16
    int chunk = BATCH, ksplit = KSMAX;
    while (chunk > 128 &&
           wbytes + (size_t)chunk * K_TOT * 2 +
           (size_t)(KSMAX - 1) * chunk * N_OUT * 2 > ws_size) chunk >>= 1;
    while (ksplit > 1 &&
           wbytes + (size_t)chunk * K_TOT * 2 +
           (size_t)(ksplit - 1) * chunk * N_OUT * 2 > ws_size) ksplit--;

    unsigned short* Abuf = Wb + (size_t)N_OUT * K_TOT;
    unsigned short* part = Abuf + (size_t)chunk * K_TOT;
    const int kiters = (K_TOT / BK) / ksplit;              // 112/ks, exact (even)

    bool first = true;
    for (int row0 = 0; row0 < BATCH; row0 += chunk) {
        int nw = first ? N_OUT : 0;                        // wconv rides launch 1
        first = false;
        kan_aux<<<dim3(chunk + nw), 256, 0, stream>>>(
            x, Abuf, base_w, spline_w, Wb, row0, chunk);
        kan_gemm<<<dim3(chunk / BM, N_OUT / BN, ksplit), 256, 0, stream>>>(
            Abuf, Wb, base_b, out, part, row0, kiters, chunk);
        if (ksplit > 1) {
            long n4 = (long)chunk * N_OUT / 4;
            kan_reduce<<<dim3((n4 + 255) / 256), 256, 0, stream>>>(
                out + (long)row0 * N_OUT, part, ksplit - 1, n4);
        }
    }
}

// Round 11
// 175.492 us; speedup vs baseline: 1.8837x; 1.0417x over previous
//
#include <hip/hip_runtime.h>
#include <hip/hip_bf16.h>

// KAN layer as one bf16 GEMM: out[8192,512] = A[8192,7168] @ W[512,7168]^T + b
// A layout is BASIS-MAJOR: col k = plane*512 + i, plane 0 = silu(x_i),
// planes 1..13 = b-spline bases g=0..12 of x_i. W permuted to match.
// R3: m97-style GEMM (global_load_lds w16, 128x128 tile) + split-K partials.
// R4: prep rewritten — register-only, __expf, coalesced ushort2 plane stores.
// R5: LDS XOR bank swizzle -> conflicts 2.2e7 -> 0 (for 16x16 reads).
// R6: 32x32x16 MFMA (VALUBusy 35->11%) + bf16 partials.
// R7: row-aware swizzle key (R&7)^((R>>3)&7) -> conflicts 0, gemm 75.5us.
// R8: ksplit 4->2 + wconv merged into prep launch. gemm 72.6us, total 178. BEST.
// R9 FAILED (gemm 244us): fused flag-race combine — 64-transaction stores +
//     device fences stalled co-resident K-loops. Reverted.
// R10 FAILED (gemm 77.5us): explicit LDS dbuf — reproduces m99/m100: implicit
//     wave overlap already captures it; 64KB LDS only adds overhead. Reverted.
// R11: R8 K-loop verbatim + symmetric bf16 partials (both ks blocks write
//     bf16 slabs; reduce combines + bias). -17MB epilogue traffic.

#define BATCH   8192
#define IN_F    512
#define N_OUT   512
#define NG      13            // GRID_SIZE + K
#define NPL     14            // planes: silu + 13 bases
#define K_TOT   7168          // 14 * 512
#define BM      128
#define BN      128
#define BK      64
#define KSMAX   2

typedef short short8 __attribute__((ext_vector_type(8)));
typedef float floatx16 __attribute__((ext_vector_type(16)));

__device__ __forceinline__ unsigned short f2bf(float f) {
    union { float f; unsigned u; } v; v.f = f;
    unsigned r = v.u + 0x7FFFu + ((v.u >> 16) & 1u);   // RNE
    return (unsigned short)(r >> 16);
}
__device__ __forceinline__ float bf2f(unsigned short h) {
    union { unsigned u; float f; } v; v.u = (unsigned)h << 16;
    return v.f;
}

__device__ __forceinline__ void gl2lds16(const unsigned short* g, unsigned short* l) {
    __builtin_amdgcn_global_load_lds(
        (const __attribute__((address_space(1))) unsigned int*)g,
        (__attribute__((address_space(3))) unsigned int*)l, 16, 0, 0);
}

// ---------------- aux: prep (blocks [0,nprep)) + wconv (blocks [nprep,nprep+nw)) ----
__global__ __launch_bounds__(256)
void kan_aux(const float* __restrict__ X,
             unsigned short* __restrict__ A,
             const float* __restrict__ base_w,
             const float* __restrict__ spline_w,
             unsigned short* __restrict__ Wb,
             int row0, int nprep) {
    if ((int)blockIdx.x >= nprep) {
        // ---- wconv part: Wb[o][pl*512+i] ----
        int o = blockIdx.x - nprep;            // 0..511
        for (int c = threadIdx.x; c < K_TOT; c += 256) {
            int pl = c >> 9;
            int i  = c & 511;
            float v = (pl == 0) ? base_w[o * IN_F + i]
                                : spline_w[(long)o * (IN_F * NG) + i * NG + (pl - 1)];
            Wb[(long)o * K_TOT + c] = f2bf(v);
        }
        return;
    }
    // ---- prep part: one block per batch row ----
    const int b  = blockIdx.x;
    const int ip = threadIdx.x;                // feature pair 0..255
    float2 x2 = ((const float2*)(X + (long)(row0 + b) * IN_F))[ip];

    float outv[2][NPL];
#pragma unroll
    for (int e = 0; e < 2; e++) {
        float x = (e == 0) ? x2.x : x2.y;
        outv[e][0] = x * __builtin_amdgcn_rcpf(1.0f + __expf(-x));  // silu

        // cubic Cox-de Boor on uniform knots t_j = -3.2 + 0.4j
        float bb[16];
#pragma unroll
        for (int j = 0; j < 16; j++) {
            float t0 = -3.2f + 0.4f * j;
            bb[j] = (x >= t0 && x < t0 + 0.4f) ? 1.0f : 0.0f;
        }
        const float inv1 = 1.0f / (0.4f + 1e-8f);
        const float inv2 = 1.0f / (0.8f + 1e-8f);
        const float inv3 = 1.0f / (1.2f + 1e-8f);
#pragma unroll
        for (int j = 0; j < 15; j++) {
            float tj = -3.2f + 0.4f * j;
            bb[j] = (x - tj) * inv1 * bb[j] + ((tj + 0.8f) - x) * inv1 * bb[j + 1];
        }
#pragma unroll
        for (int j = 0; j < 14; j++) {
            float tj = -3.2f + 0.4f * j;
            bb[j] = (x - tj) * inv2 * bb[j] + ((tj + 1.2f) - x) * inv2 * bb[j + 1];
        }
#pragma unroll
        for (int j = 0; j < 13; j++) {
            float tj = -3.2f + 0.4f * j;
            bb[j] = (x - tj) * inv3 * bb[j] + ((tj + 1.6f) - x) * inv3 * bb[j + 1];
        }
#pragma unroll
        for (int g = 0; g < NG; g++) outv[e][1 + g] = bb[g];
    }

    unsigned short* arow = A + (long)b * K_TOT + ip * 2;
#pragma unroll
    for (int pl = 0; pl < NPL; pl++) {
        unsigned int pk = (unsigned int)f2bf(outv[0][pl]) |
                          ((unsigned int)f2bf(outv[1][pl]) << 16);
        *(unsigned int*)(arow + pl * IN_F) = pk;
    }
}

// ---------------- GEMM: m97 structure + row-aware swizzle, 32x32x16 MFMA ----------------
__global__ __launch_bounds__(256)
void kan_gemm(const unsigned short* __restrict__ A,   // [chunk][7168] bf16 bits
              const unsigned short* __restrict__ Wb,  // [512][7168]  bf16 bits
              unsigned short* __restrict__ part,      // [ks][chunk][512] bf16
              int kiters, int chunk) {
    __shared__ unsigned short As[BM * BK];   // 16 KB; swizzled layout:
    __shared__ unsigned short Bs[BN * BK];   // chunk J of row R at pos J^(R&7)^((R>>3)&7)

    const int lane = threadIdx.x & 63;
    const int wave = threadIdx.x >> 6;
    const int wm   = wave >> 1;      // 0..1
    const int wn   = wave & 1;       // 0..1
    const int l32  = lane & 31;      // mfma 32x32 row/col index
    const int hi   = lane >> 5;      // mfma k-half
    const int x7   = lane & 7;       // low swizzle key bits
    const int b32  = l32 >> 3;       // row bits 3-4 within a 32-row fragment

    const int m0 = blockIdx.x * BM;          // row within chunk
    const int n0 = blockIdx.y * BN;
    const int ks = blockIdx.z;
    const long kbase = (long)ks * kiters * BK;

    // staging: instr q of wave w covers rows w*32+q*8+sr; lane l fetches
    // global chunk (l&7) ^ key(R), key(R) = (R&7)^((R>>3)&7) = sr^(4*(w&1)+q)
    const int sr = lane >> 3;                // 0..7

    const unsigned short* gA[4];
    const unsigned short* gB[4];
#pragma unroll
    for (int q = 0; q < 4; q++) {
        int scs = ((lane & 7) ^ sr ^ ((4 * (wave & 1) + q) & 7)) * 8;
        gA[q] = A  + (long)(m0 + wave * 32 + q * 8 + sr) * K_TOT + kbase + scs;
        gB[q] = Wb + (long)(n0 + wave * 32 + q * 8 + sr) * K_TOT + kbase + scs;
    }
    unsigned short* lA = As + (wave * 32) * BK;   // wave-uniform base
    unsigned short* lB = Bs + (wave * 32) * BK;

    floatx16 acc[2][2];
#pragma unroll
    for (int i = 0; i < 2; i++)
#pragma unroll
        for (int j = 0; j < 2; j++)
#pragma unroll
            for (int r = 0; r < 16; r++) acc[i][j][r] = 0.0f;

    for (int kk = 0; kk < kiters; kk++) {
        __syncthreads();                     // prior compute done before overwrite
#pragma unroll
        for (int q = 0; q < 4; q++) {
            gl2lds16(gA[q], lA + q * 8 * BK);
            gl2lds16(gB[q], lB + q * 8 * BK);
            gA[q] += BK; gB[q] += BK;
        }
        __syncthreads();                     // drains vmcnt (compiler-inserted)

#pragma unroll
        for (int s = 0; s < 4; s++) {        // four k=16 MFMA steps per BK=64
            short8 af[2], bf[2];
#pragma unroll
            for (int t = 0; t < 2; t++) {    // physical chunk = J ^ key(row)
                const int cofs = (((2 * s + hi) ^ x7 ^ (4 * t) ^ b32) & 7) * 8;
                af[t] = *(const short8*)(As + (wm * 64 + t * 32 + l32) * BK + cofs);
                bf[t] = *(const short8*)(Bs + (wn * 64 + t * 32 + l32) * BK + cofs);
            }
#pragma unroll
            for (int i = 0; i < 2; i++)
#pragma unroll
                for (int j = 0; j < 2; j++)
                    acc[i][j] = __builtin_amdgcn_mfma_f32_32x32x16_bf16(
                        af[i], bf[j], acc[i][j], 0, 0, 0);
        }
    }

    // epilogue: bf16 partial slab (symmetric for both ks)
    // 32x32 C/D layout: col=lane&31, row=(reg&3)+8*(reg>>2)+4*hi
    unsigned short* dst = part + (long)ks * chunk * N_OUT;
#pragma unroll
    for (int i = 0; i < 2; i++) {
        int r0 = m0 + wm * 64 + i * 32 + 4 * hi;
#pragma unroll
        for (int j = 0; j < 2; j++) {
            int col = n0 + wn * 64 + j * 32 + l32;
#pragma unroll
            for (int reg = 0; reg < 16; reg++) {
                int row = r0 + (reg & 3) + 8 * (reg >> 2);
                dst[(long)row * N_OUT + col] = f2bf(acc[i][j][reg]);
            }
        }
    }
}

// ---------------- combine: out = part0 + part1 + bias ----------------
__global__ void kan_reduce(float* __restrict__ out,               // chunk*512 fp32
                           const unsigned short* __restrict__ part,
                           const float* __restrict__ bias,
                           int ns, long n4) {                     // n4 = chunk*512/4
    long t = (long)blockIdx.x * 256 + threadIdx.x;
    if (t >= n4) return;
    float4 v = ((const float4*)bias)[t & 127];                    // col = (t&127)*4
    for (int s = 0; s < ns; s++) {
        ushort4 p = ((const ushort4*)part)[s * n4 + t];
        v.x += bf2f(p.x); v.y += bf2f(p.y); v.z += bf2f(p.z); v.w += bf2f(p.w);
    }
    ((float4*)out)[t] = v;
}

extern "C" void kernel_launch(void* const* d_in, const int* in_sizes, int n_in,
                              void* d_out, int out_size, void* d_ws, size_t ws_size,
                              hipStream_t stream) {
    const float* x        = (const float*)d_in[0];
    const float* base_w   = (const float*)d_in[1];
    const float* base_b   = (const float*)d_in[2];
    const float* spline_w = (const float*)d_in[3];
    float* out = (float*)d_out;

    unsigned short* Wb = (unsigned short*)d_ws;            // 512*7168 bf16
    const size_t wbytes = (size_t)N_OUT * K_TOT * 2;       // 7.34 MB

    // pick largest chunk that fits ws:
    //   ws = Wb + A[chunk][7168] bf16 + partials ksplit*chunk*512 bf16
    int chunk = BATCH, ksplit = KSMAX;
    while (chunk > 128 &&
           wbytes + (size_t)chunk * K_TOT * 2 +
           (size_t)KSMAX * chunk * N_OUT * 2 > ws_size) chunk >>= 1;

    unsigned short* Abuf = Wb + (size_t)N_OUT * K_TOT;
    unsigned short* part = Abuf + (size_t)chunk * K_TOT;
    const int kiters = (K_TOT / BK) / ksplit;              // 56, exact

    bool first = true;
    for (int row0 = 0; row0 < BATCH; row0 += chunk) {
        int nw = first ? N_OUT : 0;                        // wconv rides launch 1
        first = false;
        kan_aux<<<dim3(chunk + nw), 256, 0, stream>>>(
            x, Abuf, base_w, spline_w, Wb, row0, chunk);
        kan_gemm<<<dim3(chunk / BM, N_OUT / BN, ksplit), 256, 0, stream>>>(
            Abuf, Wb, part, kiters, chunk);
        long n4 = (long)chunk * N_OUT / 4;
        kan_reduce<<<dim3((n4 + 255) / 256), 256, 0, stream>>>(
            out + (long)row0 * N_OUT, part, base_b, ksplit, n4);
    }
}